// Round 1
// baseline (261.289 us; speedup 1.0000x reference)
//
#include <hip/hip_runtime.h>
#include <hip/hip_bf16.h>

typedef __attribute__((ext_vector_type(8))) short short8_t;
typedef __attribute__((ext_vector_type(4))) short short4_t;
typedef __attribute__((ext_vector_type(2))) short short2_t;
typedef __attribute__((ext_vector_type(4))) float f32x4;

static constexpr int B = 4, H = 16, S = 2048, D = 64;
static constexpr int QBLK = 64, KVBLK = 64, NT = S / KVBLK;
static constexpr int LDK = 72;   // padded row length in bf16 elems: 144 B, 16B-aligned

// float -> bf16 bits, round-to-nearest-even (inputs are finite normals; no NaN handling needed)
__device__ __forceinline__ short f2bf(float f) {
    unsigned u = __builtin_bit_cast(unsigned, f);
    u += 0x7fffu + ((u >> 16) & 1u);
    return (short)(u >> 16);
}

__global__ void __launch_bounds__(256)
attn_fwd(const float* __restrict__ q, const float* __restrict__ k,
         const float* __restrict__ v, float* __restrict__ out) {
    __shared__ short Ks[KVBLK][LDK];   // K tile, row-major [key][d]
    __shared__ short Vt[D][LDK];       // V tile, transposed [d][kv]
    __shared__ short Pl[4][16][LDK];   // per-wave P tile [qrow][kv]

    const int tid  = threadIdx.x;
    const int wave = tid >> 6;
    const int lane = tid & 63;
    const int l15  = lane & 15;
    const int g    = lane >> 4;

    const long base  = (long)blockIdx.y * S * D;   // (b,h) offset
    const int  qrow0 = blockIdx.x * QBLK + wave * 16;

    // ---- Q fragments (A operand), softmax scale folded in. d = c*32 + g*8 + i ----
    short8_t qf[2];
    {
        const float* qp = q + base + (long)(qrow0 + l15) * D + g * 8;
        #pragma unroll
        for (int c = 0; c < 2; ++c) {
            const f32x4 a = *reinterpret_cast<const f32x4*>(qp + c * 32);
            const f32x4 b = *reinterpret_cast<const f32x4*>(qp + c * 32 + 4);
            #pragma unroll
            for (int i = 0; i < 4; ++i) {
                qf[c][i]     = f2bf(a[i] * 0.125f);
                qf[c][4 + i] = f2bf(b[i] * 0.125f);
            }
        }
    }

    f32x4 o[4];
    float m[4], l[4];
    #pragma unroll
    for (int r = 0; r < 4; ++r) { m[r] = -INFINITY; l[r] = 0.f; }
    #pragma unroll
    for (int dc = 0; dc < 4; ++dc) o[dc] = f32x4{0.f, 0.f, 0.f, 0.f};

    for (int t = 0; t < NT; ++t) {
        __syncthreads();   // protect LDS tiles from previous iteration's readers

        // ---- stage K tile: fp32 global (coalesced float4) -> bf16 LDS row-major ----
        const float* kp = k + base + (long)t * KVBLK * D;
        #pragma unroll
        for (int it = 0; it < 4; ++it) {
            const int idx = it * 256 + tid;          // float4 index
            const int row = idx >> 4, c4 = (idx & 15) * 4;
            const f32x4 f = *reinterpret_cast<const f32x4*>(kp + row * D + c4);
            short4_t s4;
            #pragma unroll
            for (int i = 0; i < 4; ++i) s4[i] = f2bf(f[i]);
            *reinterpret_cast<short4_t*>(&Ks[row][c4]) = s4;
        }

        // ---- stage V^T: coalesced scalar rows -> bf16x2 LDS column writes ----
        const float* vp = v + base + (long)t * KVBLK * D;
        #pragma unroll
        for (int it = 0; it < 8; ++it) {
            const int tau = it * 256 + tid;
            const int d = tau & 63, kv = (tau >> 6) * 2;
            short2_t s2;
            s2[0] = f2bf(vp[kv * D + d]);
            s2[1] = f2bf(vp[(kv + 1) * D + d]);
            *reinterpret_cast<short2_t*>(&Vt[d][kv]) = s2;
        }
        __syncthreads();

        // ---- S = Q K^T (16 q-rows x 64 keys per wave) ----
        f32x4 sc[4];
        #pragma unroll
        for (int kc = 0; kc < 4; ++kc) {
            f32x4 acc = f32x4{0.f, 0.f, 0.f, 0.f};
            #pragma unroll
            for (int c = 0; c < 2; ++c) {
                const short8_t kf =
                    *reinterpret_cast<const short8_t*>(&Ks[kc * 16 + l15][c * 32 + g * 8]);
                acc = __builtin_amdgcn_mfma_f32_16x16x32_bf16(qf[c], kf, acc, 0, 0, 0);
            }
            sc[kc] = acc;
        }

        // ---- online softmax (row r lives in one 16-lane group; shfl masks 1,2,4,8) ----
        float p[4][4];
        #pragma unroll
        for (int r = 0; r < 4; ++r) {
            float pm = fmaxf(fmaxf(sc[0][r], sc[1][r]), fmaxf(sc[2][r], sc[3][r]));
            #pragma unroll
            for (int msk = 1; msk <= 8; msk <<= 1)
                pm = fmaxf(pm, __shfl_xor(pm, msk, 64));
            const float nm    = fmaxf(m[r], pm);
            const float alpha = __expf(m[r] - nm);
            float rs = 0.f;
            #pragma unroll
            for (int kc = 0; kc < 4; ++kc) {
                const float e = __expf(sc[kc][r] - nm);
                p[kc][r] = e;
                rs += e;
            }
            #pragma unroll
            for (int msk = 1; msk <= 8; msk <<= 1)
                rs += __shfl_xor(rs, msk, 64);
            l[r] = l[r] * alpha + rs;
            m[r] = nm;
            #pragma unroll
            for (int dc = 0; dc < 4; ++dc) o[dc][r] *= alpha;
        }

        // ---- P: C-layout regs -> per-wave LDS (A-layout transpose) ----
        #pragma unroll
        for (int r = 0; r < 4; ++r) {
            #pragma unroll
            for (int kc = 0; kc < 4; ++kc)
                Pl[wave][g * 4 + r][kc * 16 + l15] = f2bf(p[kc][r]);
        }
        asm volatile("s_waitcnt lgkmcnt(0)" ::: "memory");
        __builtin_amdgcn_sched_barrier(0);   // rule #18: keep MFMA from hoisting past the wait

        // ---- O += P V ----
        #pragma unroll
        for (int c = 0; c < 2; ++c) {
            const short8_t pf =
                *reinterpret_cast<const short8_t*>(&Pl[wave][l15][c * 32 + g * 8]);
            #pragma unroll
            for (int dc = 0; dc < 4; ++dc) {
                const short8_t vf =
                    *reinterpret_cast<const short8_t*>(&Vt[dc * 16 + l15][c * 32 + g * 8]);
                o[dc] = __builtin_amdgcn_mfma_f32_16x16x32_bf16(pf, vf, o[dc], 0, 0, 0);
            }
        }
    }

    // ---- epilogue: O / l ----
    float* op = out + base + (long)qrow0 * D;
    #pragma unroll
    for (int r = 0; r < 4; ++r) {
        const float inv = 1.f / l[r];
        #pragma unroll
        for (int dc = 0; dc < 4; ++dc)
            op[(g * 4 + r) * D + dc * 16 + l15] = o[dc][r] * inv;
    }
}

extern "C" void kernel_launch(void* const* d_in, const int* in_sizes, int n_in,
                              void* d_out, int out_size, void* d_ws, size_t ws_size,
                              hipStream_t stream) {
    const float* q = (const float*)d_in[0];
    const float* k = (const float*)d_in[1];
    const float* v = (const float*)d_in[2];
    float* out = (float*)d_out;
    dim3 grid(S / QBLK, B * H);
    attn_fwd<<<grid, 256, 0, stream>>>(q, k, v, out);
}

// Round 3
// 129.487 us; speedup vs baseline: 2.0179x; 2.0179x over previous
//
#include <hip/hip_runtime.h>
#include <hip/hip_bf16.h>

typedef __attribute__((ext_vector_type(8))) short short8_t;
typedef __attribute__((ext_vector_type(4))) float f32x4;
typedef __attribute__((ext_vector_type(16))) float f32x16;
typedef __attribute__((ext_vector_type(4))) unsigned u32x4;

static constexpr int B = 4, H = 16, S = 2048, D = 64;
static constexpr int WAVES = 8, QW = 32, QBLK = WAVES * QW;   // 256 q-rows/block
static constexpr int KVBLK = 64, NT = S / KVBLK;              // 32 kv tiles
static constexpr int LDK = 72;  // 144 B rows: 16B-aligned, reads hit the 8-phase LDS floor

__device__ __forceinline__ unsigned pk2(float a, float b) {
    __hip_bfloat162 h = __float22bfloat162_rn(float2{a, b});   // v_cvt_pk_bf16_f32
    unsigned u;
    __builtin_memcpy(&u, &h, 4);
    return u;
}
__device__ __forceinline__ short bf1(float a) {
    __hip_bfloat16 h = __float2bfloat16(a);
    short s;
    __builtin_memcpy(&s, &h, 2);
    return s;
}

// PV A-fragment assembly from packed P dwords (own cd + partner sw), k-step KS (h = KS&1).
// hi=0 lane needs keys 16h+0..7 -> {cd[2h][0..1], sw[2h][0..1]};
// hi=1 lane needs keys 16h+8..15 -> {sw[2h+1][0..1], cd[2h+1][0..1]}.
#define PV_STEP(CD, SW, H, KS)                                                           \
    do {                                                                                 \
        const unsigned d0 = hi ? SW[(2 * (H) + 1) * 2 + 0] : CD[(2 * (H)) * 2 + 0];      \
        const unsigned d1 = hi ? SW[(2 * (H) + 1) * 2 + 1] : CD[(2 * (H)) * 2 + 1];      \
        const unsigned d2 = hi ? CD[(2 * (H) + 1) * 2 + 0] : SW[(2 * (H)) * 2 + 0];      \
        const unsigned d3 = hi ? CD[(2 * (H) + 1) * 2 + 1] : SW[(2 * (H)) * 2 + 1];      \
        const u32x4 pu = {d0, d1, d2, d3};                                               \
        const short8_t pa = __builtin_bit_cast(short8_t, pu);                            \
        const short8_t vfa =                                                             \
            *reinterpret_cast<const short8_t*>(&Vt[ql][(KS) * 16 + hi * 8]);             \
        const short8_t vfb =                                                             \
            *reinterpret_cast<const short8_t*>(&Vt[32 + ql][(KS) * 16 + hi * 8]);        \
        Od0 = __builtin_amdgcn_mfma_f32_32x32x16_bf16(pa, vfa, Od0, 0, 0, 0);            \
        Od1 = __builtin_amdgcn_mfma_f32_32x32x16_bf16(pa, vfb, Od1, 0, 0, 0);            \
    } while (0)

__global__ void __launch_bounds__(512, 2)
attn_fwd(const float* __restrict__ q, const float* __restrict__ k,
         const float* __restrict__ v, float* __restrict__ out) {
    __shared__ short Ks[KVBLK][LDK];   // K tile row-major [key][d]
    __shared__ short Vt[D][LDK];       // V tile transposed [d][key]
    __shared__ float Xl[WAVES][QW];    // per-wave q-row broadcast (alpha / 1/l)

    const int tid  = threadIdx.x;
    const int wave = tid >> 6;
    const int lane = tid & 63;
    const int ql   = lane & 31;
    const int hi   = lane >> 5;

    const long base = (long)blockIdx.y * S * D;
    const int  q0w  = blockIdx.x * QBLK + wave * QW;

    // ---- Q fragments (B operand of swapped QK^T), scale 1/8 folded in ----
    short8_t qf[4];
    {
        const float* qp = q + base + (long)(q0w + ql) * D;
        #pragma unroll
        for (int kc = 0; kc < 4; ++kc) {
            const f32x4 a = *reinterpret_cast<const f32x4*>(qp + kc * 16 + hi * 8);
            const f32x4 b = *reinterpret_cast<const f32x4*>(qp + kc * 16 + hi * 8 + 4);
            const u32x4 u = {pk2(a[0] * 0.125f, a[1] * 0.125f),
                             pk2(a[2] * 0.125f, a[3] * 0.125f),
                             pk2(b[0] * 0.125f, b[1] * 0.125f),
                             pk2(b[2] * 0.125f, b[3] * 0.125f)};
            qf[kc] = __builtin_bit_cast(short8_t, u);
        }
    }

    f32x16 Od0, Od1;
    #pragma unroll
    for (int r = 0; r < 16; ++r) { Od0[r] = 0.f; Od1[r] = 0.f; }
    float m_r = -60.f, l_r = 0.f;

    // staging assignments (512 threads, 4096 elems/tile each for K and V)
    const int kr = tid >> 3, kc0 = (tid & 7) * 8;   // K: 8 d's of one key row (coalesced)
    const int vk = tid & 63, vd0 = (tid >> 6) * 8;  // V: 8 d's of one key row (strided global)
    const float* kbase = k + base + (long)kr * D + kc0;
    const float* vbase = v + base + (long)vk * D + vd0;

    // preload tile 0 into registers
    f32x4 kf0 = *reinterpret_cast<const f32x4*>(kbase);
    f32x4 kf1 = *reinterpret_cast<const f32x4*>(kbase + 4);
    f32x4 vf0 = *reinterpret_cast<const f32x4*>(vbase);
    f32x4 vf1 = *reinterpret_cast<const f32x4*>(vbase + 4);

    for (int t = 0; t < NT; ++t) {
        __syncthreads();   // previous tile's readers done
        // ---- write staged registers -> LDS ----
        {
            const u32x4 u = {pk2(kf0[0], kf0[1]), pk2(kf0[2], kf0[3]),
                             pk2(kf1[0], kf1[1]), pk2(kf1[2], kf1[3])};
            *reinterpret_cast<u32x4*>(&Ks[kr][kc0]) = u;   // conflict-free at floor
            #pragma unroll
            for (int j = 0; j < 4; ++j) {                  // contiguous b16 writes: conflict-free
                Vt[vd0 + j][vk]     = bf1(vf0[j]);
                Vt[vd0 + 4 + j][vk] = bf1(vf1[j]);
            }
        }
        __syncthreads();

        // ---- prefetch next tile (overlaps with compute below) ----
        if (t + 1 < NT) {
            const long off = (long)(t + 1) * KVBLK * D;
            kf0 = *reinterpret_cast<const f32x4*>(kbase + off);
            kf1 = *reinterpret_cast<const f32x4*>(kbase + off + 4);
            vf0 = *reinterpret_cast<const f32x4*>(vbase + off);
            vf1 = *reinterpret_cast<const f32x4*>(vbase + off + 4);
        }

        // ---- swapped QK^T: D[key][q] = K . Q^T ----
        f32x16 sA, sB;
        #pragma unroll
        for (int r = 0; r < 16; ++r) { sA[r] = 0.f; sB[r] = 0.f; }
        #pragma unroll
        for (int kc = 0; kc < 4; ++kc) {
            const short8_t ka = *reinterpret_cast<const short8_t*>(&Ks[ql][kc * 16 + hi * 8]);
            sA = __builtin_amdgcn_mfma_f32_32x32x16_bf16(ka, qf[kc], sA, 0, 0, 0);
        }
        #pragma unroll
        for (int kc = 0; kc < 4; ++kc) {
            const short8_t kb2 = *reinterpret_cast<const short8_t*>(&Ks[32 + ql][kc * 16 + hi * 8]);
            sB = __builtin_amdgcn_mfma_f32_32x32x16_bf16(kb2, qf[kc], sB, 0, 0, 0);
        }

        // ---- online softmax, in-lane + one cross-half exchange ----
        float pmax = sA[0];
        #pragma unroll
        for (int r = 1; r < 16; ++r) pmax = fmaxf(pmax, sA[r]);
        #pragma unroll
        for (int r = 0; r < 16; ++r) pmax = fmaxf(pmax, sB[r]);
        pmax = fmaxf(pmax, __shfl_xor(pmax, 32, 64));

        if (!__all(pmax <= m_r + 8.f)) {   // T13 defer-max: fires ~only on tile 0
            const float nm    = fmaxf(m_r, pmax);
            const float alpha = __expf(m_r - nm);
            m_r = nm;
            l_r *= alpha;
            Xl[wave][ql] = alpha;          // per-wave, in-order LDS: no barrier needed
            #pragma unroll
            for (int r = 0; r < 16; ++r) {
                const float a2 = Xl[wave][(r & 3) + 8 * (r >> 2) + 4 * hi];
                Od0[r] *= a2;
                Od1[r] *= a2;
            }
        }

        float rs = 0.f;
        #pragma unroll
        for (int r = 0; r < 16; ++r) { const float e = __expf(sA[r] - m_r); sA[r] = e; rs += e; }
        #pragma unroll
        for (int r = 0; r < 16; ++r) { const float e = __expf(sB[r] - m_r); sB[r] = e; rs += e; }
        rs += __shfl_xor(rs, 32, 64);
        l_r += rs;

        // ---- P -> bf16 pairs in-register, exchange halves (T12) ----
        unsigned cdA[8], cdB[8], swA[8], swB[8];
        #pragma unroll
        for (int jj = 0; jj < 8; ++jj) {
            cdA[jj] = pk2(sA[jj * 2], sA[jj * 2 + 1]);
            cdB[jj] = pk2(sB[jj * 2], sB[jj * 2 + 1]);
        }
        #pragma unroll
        for (int jj = 0; jj < 8; ++jj) {
            swA[jj] = (unsigned)__shfl_xor((int)cdA[jj], 32, 64);
            swB[jj] = (unsigned)__shfl_xor((int)cdB[jj], 32, 64);
        }

        // ---- O += P V ----
        PV_STEP(cdA, swA, 0, 0);
        PV_STEP(cdA, swA, 1, 1);
        PV_STEP(cdB, swB, 0, 2);
        PV_STEP(cdB, swB, 1, 3);
    }

    // ---- epilogue: O / l (1/l broadcast across the q-row's lanes via LDS) ----
    Xl[wave][ql] = 1.f / l_r;
    float* op = out + base + (long)q0w * D + ql;
    #pragma unroll
    for (int r = 0; r < 16; ++r) {
        const int   row = (r & 3) + 8 * (r >> 2) + 4 * hi;
        const float s   = Xl[wave][row];
        op[(long)row * D]      = Od0[r] * s;
        op[(long)row * D + 32] = Od1[r] * s;
    }
}

extern "C" void kernel_launch(void* const* d_in, const int* in_sizes, int n_in,
                              void* d_out, int out_size, void* d_ws, size_t ws_size,
                              hipStream_t stream) {
    const float* q = (const float*)d_in[0];
    const float* k = (const float*)d_in[1];
    const float* v = (const float*)d_in[2];
    float* out = (float*)d_out;
    dim3 grid(S / QBLK, B * H);
    attn_fwd<<<grid, 512, 0, stream>>>(q, k, v, out);
}

// Round 4
// 114.941 us; speedup vs baseline: 2.2733x; 1.1266x over previous
//
#include <hip/hip_runtime.h>
#include <hip/hip_bf16.h>

typedef __attribute__((ext_vector_type(8))) short short8_t;
typedef __attribute__((ext_vector_type(4))) float f32x4;
typedef __attribute__((ext_vector_type(16))) float f32x16;
typedef __attribute__((ext_vector_type(4))) unsigned u32x4;

static constexpr int B = 4, H = 16, S = 2048, D = 64;
static constexpr int WAVES = 8, QW = 32, QBLK = WAVES * QW;   // 256 q-rows/block
static constexpr int KVBLK = 64, NT = S / KVBLK;              // 32 kv tiles
static constexpr int LDK = 72;  // 144 B rows: b128 reads phase 8 lanes over all 32 banks -> conflict-free

// softmax in log2 domain: scale = (1/sqrt(64)) * log2(e)
#define QSCALE 0.18033688011112042f
#define DEFER_THR 11.54f   // = 8 * log2(e)

__device__ __forceinline__ unsigned pk2(float a, float b) {
    __hip_bfloat162 h = __float22bfloat162_rn(float2{a, b});   // v_cvt_pk_bf16_f32
    unsigned u;
    __builtin_memcpy(&u, &h, 4);
    return u;
}

__device__ __forceinline__ float fexp2(float x) {
#if __has_builtin(__builtin_amdgcn_exp2f)
    return __builtin_amdgcn_exp2f(x);   // raw v_exp_f32
#else
    return exp2f(x);
#endif
}

// PV A-fragment assembly from packed P dwords (own cd + partner sw), k-step KS (h = KS&1).
// (empirically validated in R3 — do not touch)
#define PV_STEP(CD, SW, H, KS)                                                           \
    do {                                                                                 \
        const unsigned d0 = hi ? SW[(2 * (H) + 1) * 2 + 0] : CD[(2 * (H)) * 2 + 0];      \
        const unsigned d1 = hi ? SW[(2 * (H) + 1) * 2 + 1] : CD[(2 * (H)) * 2 + 1];      \
        const unsigned d2 = hi ? CD[(2 * (H) + 1) * 2 + 0] : SW[(2 * (H)) * 2 + 0];      \
        const unsigned d3 = hi ? CD[(2 * (H) + 1) * 2 + 1] : SW[(2 * (H)) * 2 + 1];      \
        const u32x4 pu = {d0, d1, d2, d3};                                               \
        const short8_t pa = __builtin_bit_cast(short8_t, pu);                            \
        const short8_t vfa =                                                             \
            *reinterpret_cast<const short8_t*>(&Vt[cb][ql][(KS) * 16 + hi * 8]);         \
        const short8_t vfb =                                                             \
            *reinterpret_cast<const short8_t*>(&Vt[cb][32 + ql][(KS) * 16 + hi * 8]);    \
        Od0 = __builtin_amdgcn_mfma_f32_32x32x16_bf16(pa, vfa, Od0, 0, 0, 0);            \
        Od1 = __builtin_amdgcn_mfma_f32_32x32x16_bf16(pa, vfb, Od1, 0, 0, 0);            \
    } while (0)

__global__ void __launch_bounds__(512, 2)
attn_fwd(const float* __restrict__ q, const float* __restrict__ k,
         const float* __restrict__ v, float* __restrict__ out) {
    __shared__ short Ks[2][KVBLK][LDK];   // K tiles row-major [key][d], double-buffered
    __shared__ short Vt[2][D][LDK];       // V tiles transposed [d][key], double-buffered
    __shared__ float Xl[WAVES][QW];       // per-wave q-row broadcast (alpha / 1/l)

    const int tid  = threadIdx.x;
    const int wave = tid >> 6;
    const int lane = tid & 63;
    const int ql   = lane & 31;
    const int hi   = lane >> 5;

    const long base = (long)blockIdx.y * S * D;
    const int  q0w  = blockIdx.x * QBLK + wave * QW;

    // ---- Q fragments (B operand of swapped QK^T), log2-domain scale folded in ----
    short8_t qf[4];
    {
        const float* qp = q + base + (long)(q0w + ql) * D;
        #pragma unroll
        for (int kc = 0; kc < 4; ++kc) {
            const f32x4 a = *reinterpret_cast<const f32x4*>(qp + kc * 16 + hi * 8);
            const f32x4 b = *reinterpret_cast<const f32x4*>(qp + kc * 16 + hi * 8 + 4);
            const u32x4 u = {pk2(a[0] * QSCALE, a[1] * QSCALE),
                             pk2(a[2] * QSCALE, a[3] * QSCALE),
                             pk2(b[0] * QSCALE, b[1] * QSCALE),
                             pk2(b[2] * QSCALE, b[3] * QSCALE)};
            qf[kc] = __builtin_bit_cast(short8_t, u);
        }
    }

    f32x16 Od0, Od1;
    #pragma unroll
    for (int r = 0; r < 16; ++r) { Od0[r] = 0.f; Od1[r] = 0.f; }
    float m_r = -100.f, l_r = 0.f;   // log2 units; halves keep separate l, merged in epilogue

    // staging assignments (512 threads; 4096 elems/tile each for K and V)
    const int kr  = tid >> 3,  kc0 = (tid & 7) * 8;   // K: 8 d's of one key row
    const int vk2 = (tid & 31) * 2, vd0 = (tid >> 5) * 4;  // V: 2 keys x 4 d's
    const float* kbase  = k + base + (long)kr * D + kc0;
    const float* vbaseA = v + base + (long)vk2 * D + vd0;
    const float* vbaseB = vbaseA + D;

    // preload tile 0 into registers
    f32x4 kf0 = *reinterpret_cast<const f32x4*>(kbase);
    f32x4 kf1 = *reinterpret_cast<const f32x4*>(kbase + 4);
    f32x4 vfA = *reinterpret_cast<const f32x4*>(vbaseA);
    f32x4 vfB = *reinterpret_cast<const f32x4*>(vbaseB);

    for (int t = 0; t < NT; ++t) {
        const int cb = t & 1;
        // ---- write staged regs (tile t) -> LDS[cb]; overlaps other waves' tile t-1 compute ----
        {
            const u32x4 ku = {pk2(kf0[0], kf0[1]), pk2(kf0[2], kf0[3]),
                              pk2(kf1[0], kf1[1]), pk2(kf1[2], kf1[3])};
            *reinterpret_cast<u32x4*>(&Ks[cb][kr][kc0]) = ku;
            #pragma unroll
            for (int j = 0; j < 4; ++j) {   // pairs (key, key+1) at fixed d: one b32 each, banks distinct
                const unsigned uv = pk2(vfA[j], vfB[j]);
                *reinterpret_cast<unsigned*>(&Vt[cb][vd0 + j][vk2]) = uv;
            }
        }
        // ---- prefetch tile t+1 (HBM latency hides under barrier + compute) ----
        if (t + 1 < NT) {
            const long off = (long)(t + 1) * KVBLK * D;
            kf0 = *reinterpret_cast<const f32x4*>(kbase + off);
            kf1 = *reinterpret_cast<const f32x4*>(kbase + off + 4);
            vfA = *reinterpret_cast<const f32x4*>(vbaseA + off);
            vfB = *reinterpret_cast<const f32x4*>(vbaseB + off);
        }
        __syncthreads();   // tile t LDS writes visible; prev-iter readers of buf[cb^1] done

        // ---- swapped QK^T: D[key][q] = K . Q^T ----
        f32x16 sA, sB;
        #pragma unroll
        for (int r = 0; r < 16; ++r) { sA[r] = 0.f; sB[r] = 0.f; }
        __builtin_amdgcn_s_setprio(1);
        #pragma unroll
        for (int kc = 0; kc < 4; ++kc) {
            const short8_t ka = *reinterpret_cast<const short8_t*>(&Ks[cb][ql][kc * 16 + hi * 8]);
            sA = __builtin_amdgcn_mfma_f32_32x32x16_bf16(ka, qf[kc], sA, 0, 0, 0);
        }
        #pragma unroll
        for (int kc = 0; kc < 4; ++kc) {
            const short8_t kb2 = *reinterpret_cast<const short8_t*>(&Ks[cb][32 + ql][kc * 16 + hi * 8]);
            sB = __builtin_amdgcn_mfma_f32_32x32x16_bf16(kb2, qf[kc], sB, 0, 0, 0);
        }
        __builtin_amdgcn_s_setprio(0);

        // ---- online softmax (log2 domain): tree max, in-lane exp2, split-l ----
        float mp[8];
        #pragma unroll
        for (int i = 0; i < 8; ++i)
            mp[i] = fmaxf(fmaxf(sA[2 * i], sA[2 * i + 1]),
                          fmaxf(sB[2 * i], sB[2 * i + 1]));
        #pragma unroll
        for (int i = 0; i < 4; ++i) mp[i] = fmaxf(mp[2 * i], mp[2 * i + 1]);
        float pmax = fmaxf(fmaxf(mp[0], mp[1]), fmaxf(mp[2], mp[3]));
        pmax = fmaxf(pmax, __shfl_xor(pmax, 32, 64));

        if (!__all(pmax <= m_r + DEFER_THR)) {   // T13: fires ~only on tile 0
            const float nm    = fmaxf(m_r, pmax);
            const float alpha = fexp2(m_r - nm);
            m_r = nm;
            l_r *= alpha;
            Xl[wave][ql] = alpha;                // per-wave private row; in-order LDS
            #pragma unroll
            for (int r = 0; r < 16; ++r) {
                const float a2 = Xl[wave][(r & 3) + 8 * (r >> 2) + 4 * hi];
                Od0[r] *= a2;
                Od1[r] *= a2;
            }
        }

        float rs0 = 0.f, rs1 = 0.f, rs2 = 0.f, rs3 = 0.f;
        #pragma unroll
        for (int r = 0; r < 16; ++r) {
            const float e = fexp2(sA[r] - m_r);
            sA[r] = e;
            if ((r & 3) == 0) rs0 += e; else if ((r & 3) == 1) rs1 += e;
            else if ((r & 3) == 2) rs2 += e; else rs3 += e;
        }
        #pragma unroll
        for (int r = 0; r < 16; ++r) {
            const float e = fexp2(sB[r] - m_r);
            sB[r] = e;
            if ((r & 3) == 0) rs0 += e; else if ((r & 3) == 1) rs1 += e;
            else if ((r & 3) == 2) rs2 += e; else rs3 += e;
        }
        l_r += (rs0 + rs1) + (rs2 + rs3);

        // ---- P -> bf16 pairs in-register, exchange halves (T12) ----
        unsigned cdA[8], cdB[8], swA[8], swB[8];
        #pragma unroll
        for (int jj = 0; jj < 8; ++jj) {
            cdA[jj] = pk2(sA[jj * 2], sA[jj * 2 + 1]);
            cdB[jj] = pk2(sB[jj * 2], sB[jj * 2 + 1]);
        }
        #pragma unroll
        for (int jj = 0; jj < 8; ++jj) {
            swA[jj] = (unsigned)__shfl_xor((int)cdA[jj], 32, 64);
            swB[jj] = (unsigned)__shfl_xor((int)cdB[jj], 32, 64);
        }

        // ---- O += P V ----
        __builtin_amdgcn_s_setprio(1);
        PV_STEP(cdA, swA, 0, 0);
        PV_STEP(cdA, swA, 1, 1);
        PV_STEP(cdB, swB, 0, 2);
        PV_STEP(cdB, swB, 1, 3);
        __builtin_amdgcn_s_setprio(0);
    }

    // ---- epilogue: merge split-l across halves, then O / l ----
    const float l_tot = l_r + __shfl_xor(l_r, 32, 64);
    Xl[wave][ql] = 1.f / l_tot;
    float* op = out + base + (long)q0w * D + ql;
    #pragma unroll
    for (int r = 0; r < 16; ++r) {
        const int   row = (r & 3) + 8 * (r >> 2) + 4 * hi;
        const float s   = Xl[wave][row];
        op[(long)row * D]      = Od0[r] * s;
        op[(long)row * D + 32] = Od1[r] * s;
    }
}

extern "C" void kernel_launch(void* const* d_in, const int* in_sizes, int n_in,
                              void* d_out, int out_size, void* d_ws, size_t ws_size,
                              hipStream_t stream) {
    const float* q = (const float*)d_in[0];
    const float* k = (const float*)d_in[1];
    const float* v = (const float*)d_in[2];
    float* out = (float*)d_out;
    dim3 grid(S / QBLK, B * H);
    attn_fwd<<<grid, 512, 0, stream>>>(q, k, v, out);
}